// Round 2
// baseline (720.853 us; speedup 1.0000x reference)
//
#include <hip/hip_runtime.h>

#define BB 32
#define NN 128
#define EE 16384
#define ROWS_E (BB*EE)     // 524288
#define ROWS_N (BB*NN)     // 4096
#define EPS_BN 1e-5f

// d_out layout (floats): h_out, x_out, m
#define XOUT_OFF (ROWS_N*72)
#define M_OFF    (XOUT_OFF + ROWS_N*4)

// ws layout (floats)
#define ST1_OFF 0
#define ST2_OFF 512
#define AGG_OFF 1024
#define CNT_OFF (AGG_OFF + ROWS_N*4)
#define MAGG_OFF (CNT_OFF + ROWS_N)
#define Z2_OFF (MAGG_OFF + ROWS_N*72)     // 316416
#define ZERO_FLOATS Z2_OFF
#define WB_OFF (Z2_OFF + ROWS_N*72)       // 611328 floats; ushort region after

// transposed bf16 weight buffer (ushort offsets)
#define WE1T_OFF 0          // [80][168]
#define WE2T_OFF 13440      // [80][104]
#define WX1T_OFF 21760      // [80][104]
#define WH1T_OFF 30080      // [80][168]
#define WH2T_OFF 43520      // [80][104]
#define WB_TOTAL 51840

typedef __attribute__((ext_vector_type(8))) short short8;
typedef __attribute__((ext_vector_type(4))) float f32x4;

__device__ __forceinline__ float psi_f(float p) {
    return copysignf(log1pf(fabsf(p)), p);
}
__device__ __forceinline__ unsigned short f2bf(float f) {
    union { float f; unsigned u; } v; v.f = f;
    unsigned r = v.u + 0x7fffu + ((v.u >> 16) & 1u);
    return (unsigned short)(r >> 16);
}
__device__ __forceinline__ unsigned pk(float a, float b) {
    return (unsigned)f2bf(a) | ((unsigned)f2bf(b) << 16);
}

// ---------- weight prep: transpose + bf16, pad n->80, k->168/104 with zeros
__global__ void k_prep(const float* __restrict__ We1, const float* __restrict__ We2,
                       const float* __restrict__ Wx1, const float* __restrict__ Wh1,
                       const float* __restrict__ Wh2, unsigned short* __restrict__ wb)
{
    int idx = blockIdx.x * 256 + threadIdx.x;
    if (idx >= WB_TOTAL) return;
    const float* src; int off, n, k, K;
    if (idx < WE2T_OFF)      { off = idx;            n = off/168; k = off%168; src = We1; K = 146; }
    else if (idx < WH1T_OFF && idx >= WX1T_OFF) { off = idx - WX1T_OFF; n = off/104; k = off%104; src = Wx1; K = 72; }
    else if (idx < WX1T_OFF) { off = idx - WE2T_OFF; n = off/104; k = off%104; src = We2; K = 72; }
    else if (idx < WH2T_OFF) { off = idx - WH1T_OFF; n = off/168; k = off%168; src = Wh1; K = 148; }
    else                     { off = idx - WH2T_OFF; n = off/104; k = off%104; src = Wh2; K = 72; }
    float v = (n < 72 && k < K) ? src[k * 72 + n] : 0.f;
    wb[idx] = f2bf(v);
}

// ---------- GEMM1: z1[524288,72] = feat[.,146] @ We1 ; feat gathered + psi feats
// LDS = At only (40960 B, stride 160) -> 4 blocks/CU. sred aliased into the wave's
// own At region (per-wave row ownership: all At reads done before stats writes).
__global__ __launch_bounds__(256, 4) void k_edge_gemm1(
    const float* __restrict__ h, const float* __restrict__ x,
    const int* __restrict__ ei, const int* __restrict__ ej,
    const unsigned short* __restrict__ We1t, float* __restrict__ z1,
    float* __restrict__ st)
{
    __shared__ unsigned short At[128 * 160];
    int tid = threadIdx.x;
    int rl = tid >> 1, half = tid & 1;
    int row = blockIdx.x * 128 + rl;
    int b = row >> 14;
    int i = ei[row], j = ej[row];
    int node = half ? j : i;
    const float4* hp = (const float4*)(h + (size_t)(b * 128 + node) * 72);
    uint2* arow = (uint2*)(&At[rl * 160 + half * 72]);
    #pragma unroll
    for (int q = 0; q < 18; q++) {
        float4 v = hp[q];
        arow[q] = make_uint2(pk(v.x, v.y), pk(v.z, v.w));
    }
    if (half == 0) {
        float4 xi = *(const float4*)(x + (size_t)(b * 128 + i) * 4);
        float4 xj = *(const float4*)(x + (size_t)(b * 128 + j) * 4);
        float d0 = xi.x - xj.x, d1 = xi.y - xj.y, d2 = xi.z - xj.z, d3 = xi.w - xj.w;
        float nrm = d0*d0 - d1*d1 - d2*d2 - d3*d3;
        float dot = xi.x*xj.x - xi.y*xj.y - xi.z*xj.z - xi.w*xj.w;
        *(unsigned*)(&At[rl * 160 + 144]) = pk(psi_f(nrm), psi_f(dot));
        unsigned* tp = (unsigned*)(&At[rl * 160 + 146]);
        tp[0] = 0u; tp[1] = 0u; tp[2] = 0u;      // k 146..151
    } else {
        unsigned* tp = (unsigned*)(&At[rl * 160 + 152]);
        tp[0] = 0u; tp[1] = 0u; tp[2] = 0u; tp[3] = 0u;  // k 152..159
    }
    // no barrier: wave wv staged exactly rows [32wv,32wv+32), the only rows it reads

    int wv = tid >> 6, lane = tid & 63, c = lane & 15, quad = lane >> 4;
    f32x4 acc[2][5] = {};
    for (int kc = 0; kc < 5; kc++) {
        int k0 = kc * 32 + quad * 8;
        short8 a0 = *(const short8*)(&At[(wv * 32 + c) * 160 + k0]);
        short8 a1 = *(const short8*)(&At[(wv * 32 + 16 + c) * 160 + k0]);
        #pragma unroll
        for (int ct = 0; ct < 5; ct++) {
            short8 bf = *(const short8*)(&We1t[(ct * 16 + c) * 168 + k0]);
            acc[0][ct] = __builtin_amdgcn_mfma_f32_16x16x32_bf16(a0, bf, acc[0][ct], 0, 0, 0);
            acc[1][ct] = __builtin_amdgcn_mfma_f32_16x16x32_bf16(a1, bf, acc[1][ct], 0, 0, 0);
        }
    }
    size_t rbase = (size_t)blockIdx.x * 128 + wv * 32 + quad * 4;
    float* sredw = (float*)(&At[wv * 32 * 160]);   // reuse own wave's staged region
    #pragma unroll
    for (int ct = 0; ct < 5; ct++) {
        int col = ct * 16 + c;
        float s = 0.f, q = 0.f;
        #pragma unroll
        for (int rt = 0; rt < 2; rt++) {
            float* op = z1 + (rbase + rt * 16) * 72 + col;
            #pragma unroll
            for (int r = 0; r < 4; r++) {
                float v = acc[rt][ct][r];
                if (col < 72) op[(size_t)r * 72] = v;
                s += v; q += v * v;
            }
        }
        s += __shfl_xor(s, 16); s += __shfl_xor(s, 32);
        q += __shfl_xor(q, 16); q += __shfl_xor(q, 32);
        if (lane < 16 && col < 72) { sredw[col] = s; sredw[72 + col] = q; }
    }
    __syncthreads();
    if (tid < 144) {
        const float* a = (const float*)At;
        atomicAdd(&st[tid], a[tid] + a[2560 + tid] + a[5120 + tid] + a[7680 + tid]);
    }
}

__global__ void k_finalize(float* __restrict__ st, float inv_rows)
{
    int c = threadIdx.x;
    if (c < 72) {
        float mean = st[c] * inv_rows;
        float var  = st[72 + c] * inv_rows - mean * mean;
        st[144 + c] = mean;
        st[216 + c] = rsqrtf(var + EPS_BN);
    }
}

// ---------- edge main: BN+ReLU -> MFMA GEMM2 -> gate -> m ; MFMA GEMM3 -> g2 -> agg/cnt
// LDS 27136 B -> 6 blocks/CU (162816 <= 163840).
__global__ __launch_bounds__(256, 6) void k_edge_main(
    const float* __restrict__ x, const int* __restrict__ ei, const int* __restrict__ ej,
    const float* __restrict__ st1, const float* __restrict__ g1, const float* __restrict__ b1,
    const float* __restrict__ be2, const float* __restrict__ Wm, const float* __restrict__ bm,
    const float* __restrict__ bx1, const float* __restrict__ Wx2,
    const unsigned short* __restrict__ We2t, const unsigned short* __restrict__ Wx1t,
    float* __restrict__ m, float* __restrict__ agg, float* __restrict__ cnt)
{
    __shared__ unsigned short Zt[128 * 104];
    __shared__ float g2buf[128];
    int tid = threadIdx.x;
    int rl = tid >> 1, half = tid & 1;
    size_t row = (size_t)blockIdx.x * 128 + rl;
    const float* mean = st1 + 144;
    const float* inv  = st1 + 216;
    const float4* zp = (const float4*)(m + row * 72) + half * 9;
    uint2* arow = (uint2*)(&Zt[rl * 104 + half * 36]);
    #pragma unroll
    for (int q = 0; q < 9; q++) {
        int k = half * 36 + q * 4;
        float4 v = zp[q];
        float a0 = fmaxf((v.x - mean[k  ]) * inv[k  ] * g1[k  ] + b1[k  ], 0.f);
        float a1 = fmaxf((v.y - mean[k+1]) * inv[k+1] * g1[k+1] + b1[k+1], 0.f);
        float a2 = fmaxf((v.z - mean[k+2]) * inv[k+2] * g1[k+2] + b1[k+2], 0.f);
        float a3 = fmaxf((v.w - mean[k+3]) * inv[k+3] * g1[k+3] + b1[k+3], 0.f);
        arow[q] = make_uint2(pk(a0, a1), pk(a2, a3));
    }
    uint2* prow = (uint2*)(&Zt[rl * 104]);
    #pragma unroll
    for (int q = 0; q < 4; q++) prow[18 + half * 4 + q] = make_uint2(0u, 0u);
    // no barrier: wave wv staged exactly its own 32 rows

    int wv = tid >> 6, lane = tid & 63, c = lane & 15, quad = lane >> 4;
    // GEMM2 (B from global, L1/L2-hit)
    f32x4 acc2[2][5] = {};
    for (int kc = 0; kc < 3; kc++) {
        int k0 = kc * 32 + quad * 8;
        short8 a0 = *(const short8*)(&Zt[(wv * 32 + c) * 104 + k0]);
        short8 a1 = *(const short8*)(&Zt[(wv * 32 + 16 + c) * 104 + k0]);
        #pragma unroll
        for (int ct = 0; ct < 5; ct++) {
            short8 bf = *(const short8*)(&We2t[(ct * 16 + c) * 104 + k0]);
            acc2[0][ct] = __builtin_amdgcn_mfma_f32_16x16x32_bf16(a0, bf, acc2[0][ct], 0, 0, 0);
            acc2[1][ct] = __builtin_amdgcn_mfma_f32_16x16x32_bf16(a1, bf, acc2[1][ct], 0, 0, 0);
        }
    }
    // epilogue: t = relu(acc+be2); gate s = sum t*Wm
    float part[2][4] = {};
    float bm0 = bm[0];
    #pragma unroll
    for (int ct = 0; ct < 5; ct++) {
        int col = ct * 16 + c;
        float bias = (col < 72) ? be2[col] : 0.f;
        float wm   = (col < 72) ? Wm[col]  : 0.f;
        #pragma unroll
        for (int rt = 0; rt < 2; rt++)
            #pragma unroll
            for (int r = 0; r < 4; r++) {
                float t = fmaxf(acc2[rt][ct][r] + bias, 0.f);
                acc2[rt][ct][r] = t;
                part[rt][r] += t * wm;
            }
    }
    float sg[2][4];
    #pragma unroll
    for (int rt = 0; rt < 2; rt++)
        #pragma unroll
        for (int r = 0; r < 4; r++) {
            float s = part[rt][r];
            s += __shfl_xor(s, 1); s += __shfl_xor(s, 2);
            s += __shfl_xor(s, 4); s += __shfl_xor(s, 8);
            sg[rt][r] = 1.f / (1.f + expf(-(s + bm0)));
        }
    // m = t * gate: write global fp32 + LDS bf16 (overwrite own wave's rows)
    size_t rbase = (size_t)blockIdx.x * 128 + wv * 32 + quad * 4;
    #pragma unroll
    for (int rt = 0; rt < 2; rt++)
        #pragma unroll
        for (int ct = 0; ct < 5; ct++) {
            int col = ct * 16 + c;
            #pragma unroll
            for (int r = 0; r < 4; r++) {
                float mv = acc2[rt][ct][r] * sg[rt][r];
                int lrow = wv * 32 + rt * 16 + quad * 4 + r;
                Zt[lrow * 104 + col] = f2bf(mv);
                if (col < 72) m[(rbase + rt * 16 + r) * 72 + col] = mv;
            }
        }
    // GEMM3: u = m @ Wx1  (same wave's rows, no barrier needed; B from global)
    f32x4 acc3[2][5] = {};
    for (int kc = 0; kc < 3; kc++) {
        int k0 = kc * 32 + quad * 8;
        short8 a0 = *(const short8*)(&Zt[(wv * 32 + c) * 104 + k0]);
        short8 a1 = *(const short8*)(&Zt[(wv * 32 + 16 + c) * 104 + k0]);
        #pragma unroll
        for (int ct = 0; ct < 5; ct++) {
            short8 bf = *(const short8*)(&Wx1t[(ct * 16 + c) * 104 + k0]);
            acc3[0][ct] = __builtin_amdgcn_mfma_f32_16x16x32_bf16(a0, bf, acc3[0][ct], 0, 0, 0);
            acc3[1][ct] = __builtin_amdgcn_mfma_f32_16x16x32_bf16(a1, bf, acc3[1][ct], 0, 0, 0);
        }
    }
    float part3[2][4] = {};
    #pragma unroll
    for (int ct = 0; ct < 5; ct++) {
        int col = ct * 16 + c;
        float bias = (col < 72) ? bx1[col] : 0.f;
        float wx   = (col < 72) ? Wx2[col] : 0.f;
        #pragma unroll
        for (int rt = 0; rt < 2; rt++)
            #pragma unroll
            for (int r = 0; r < 4; r++)
                part3[rt][r] += fmaxf(acc3[rt][ct][r] + bias, 0.f) * wx;
    }
    #pragma unroll
    for (int rt = 0; rt < 2; rt++)
        #pragma unroll
        for (int r = 0; r < 4; r++) {
            float s = part3[rt][r];
            s += __shfl_xor(s, 1); s += __shfl_xor(s, 2);
            s += __shfl_xor(s, 4); s += __shfl_xor(s, 8);
            if (c == 0) g2buf[wv * 32 + rt * 16 + quad * 4 + r] = s;
        }
    __syncthreads();
    // scatter agg/cnt
    if (tid < 128) {
        size_t erow = (size_t)blockIdx.x * 128 + tid;
        int b = (int)(erow >> 14);
        int i2 = ei[erow], j2 = ej[erow];
        float g2 = g2buf[tid];
        float4 xi = *(const float4*)(x + (size_t)(b * 128 + i2) * 4);
        float4 xj = *(const float4*)(x + (size_t)(b * 128 + j2) * 4);
        float t0 = fminf(fmaxf((xi.x - xj.x) * g2, -100.f), 100.f);
        float t1 = fminf(fmaxf((xi.y - xj.y) * g2, -100.f), 100.f);
        float t2 = fminf(fmaxf((xi.z - xj.z) * g2, -100.f), 100.f);
        float t3 = fminf(fmaxf((xi.w - xj.w) * g2, -100.f), 100.f);
        float* ap = agg + (size_t)(b * 128 + i2) * 4;
        atomicAdd(ap + 0, t0); atomicAdd(ap + 1, t1);
        atomicAdd(ap + 2, t2); atomicAdd(ap + 3, t3);
        atomicAdd(cnt + (size_t)(b * 128 + i2), 1.f);
    }
}

// ---------- magg: segment-sum of m over edges, LDS-staged (512 blocks, 1024 edges each)
__global__ __launch_bounds__(256, 4) void k_magg(
    const float* __restrict__ m, const int* __restrict__ ei, float* __restrict__ magg)
{
    __shared__ float accum[128 * 72];
    int tid = threadIdx.x;
    for (int q = tid; q < 9216; q += 256) accum[q] = 0.f;
    __syncthreads();
    int b = blockIdx.x >> 4, chunk = blockIdx.x & 15;
    int wv = tid >> 6, lane = tid & 63;
    int ebase = b * 16384 + chunk * 1024;
    for (int e = wv; e < 1024; e += 4) {
        int erow = ebase + e;
        int node = ei[erow];
        const float* mr = m + (size_t)erow * 72;
        atomicAdd(&accum[node * 72 + lane], mr[lane]);
        if (lane < 8) atomicAdd(&accum[node * 72 + 64 + lane], mr[64 + lane]);
    }
    __syncthreads();
    float* mg = magg + (size_t)b * 9216;
    for (int q = tid; q < 9216; q += 256) atomicAdd(&mg[q], accum[q]);
}

// ---------- node GEMM1: z2 = [h, magg, node_attr] @ Wh1 + bh1 ; BN stats fused
__global__ __launch_bounds__(256) void k_node_gemm1(
    const float* __restrict__ h, const float* __restrict__ node_attr,
    const float* __restrict__ magg, const unsigned short* __restrict__ Wh1t,
    const float* __restrict__ bh1, float* __restrict__ z2, float* __restrict__ st)
{
    __shared__ unsigned short At[128 * 168];
    __shared__ unsigned short Wt[80 * 168];
    __shared__ float sred[4][144];
    int tid = threadIdx.x;
    {
        const uint4* s = (const uint4*)Wh1t; uint4* d = (uint4*)Wt;
        for (int q = tid; q < 1680; q += 256) d[q] = s[q];
    }
    int rl = tid >> 1, half = tid & 1;
    size_t row = (size_t)blockIdx.x * 128 + rl;
    const float4* sp = (const float4*)((half ? magg : h) + row * 72);
    uint2* arow = (uint2*)(&At[rl * 168 + half * 72]);
    #pragma unroll
    for (int q = 0; q < 18; q++) {
        float4 v = sp[q];
        arow[q] = make_uint2(pk(v.x, v.y), pk(v.z, v.w));
    }
    if (half) {
        float4 na = *(const float4*)(node_attr + row * 4);
        *(unsigned*)(&At[rl * 168 + 144]) = pk(na.x, na.y);
        *(unsigned*)(&At[rl * 168 + 146]) = pk(na.z, na.w);
        unsigned* tailp = (unsigned*)(&At[rl * 168 + 148]);
        #pragma unroll
        for (int q = 0; q < 10; q++) tailp[q] = 0u;
    }
    __syncthreads();

    int wv = tid >> 6, lane = tid & 63, c = lane & 15, quad = lane >> 4;
    f32x4 acc[2][5] = {};
    for (int kc = 0; kc < 5; kc++) {
        int k0 = kc * 32 + quad * 8;
        short8 a0 = *(const short8*)(&At[(wv * 32 + c) * 168 + k0]);
        short8 a1 = *(const short8*)(&At[(wv * 32 + 16 + c) * 168 + k0]);
        #pragma unroll
        for (int ct = 0; ct < 5; ct++) {
            short8 bf = *(const short8*)(&Wt[(ct * 16 + c) * 168 + k0]);
            acc[0][ct] = __builtin_amdgcn_mfma_f32_16x16x32_bf16(a0, bf, acc[0][ct], 0, 0, 0);
            acc[1][ct] = __builtin_amdgcn_mfma_f32_16x16x32_bf16(a1, bf, acc[1][ct], 0, 0, 0);
        }
    }
    size_t rbase = (size_t)blockIdx.x * 128 + wv * 32 + quad * 4;
    #pragma unroll
    for (int ct = 0; ct < 5; ct++) {
        int col = ct * 16 + c;
        float bias = (col < 72) ? bh1[col] : 0.f;
        float s = 0.f, q = 0.f;
        #pragma unroll
        for (int rt = 0; rt < 2; rt++) {
            float* op = z2 + (rbase + rt * 16) * 72 + col;
            #pragma unroll
            for (int r = 0; r < 4; r++) {
                float v = acc[rt][ct][r] + bias;
                if (col < 72) op[(size_t)r * 72] = v;
                s += v; q += v * v;
            }
        }
        s += __shfl_xor(s, 16); s += __shfl_xor(s, 32);
        q += __shfl_xor(q, 16); q += __shfl_xor(q, 32);
        if (lane < 16 && col < 72) { sred[wv][col] = s; sred[wv][72 + col] = q; }
    }
    __syncthreads();
    if (tid < 144)
        atomicAdd(&st[tid], sred[0][tid] + sred[1][tid] + sred[2][tid] + sred[3][tid]);
}

// ---------- node final: BN2+ReLU -> MFMA @Wh2 + bh2 + h ; x_out
__global__ __launch_bounds__(256) void k_node_final(
    const float* __restrict__ h, const float* __restrict__ x,
    const float* __restrict__ z2, const float* __restrict__ st2,
    const float* __restrict__ gh, const float* __restrict__ bh,
    const unsigned short* __restrict__ Wh2t, const float* __restrict__ bh2,
    const float* __restrict__ agg, const float* __restrict__ cnt,
    float* __restrict__ hout, float* __restrict__ xout)
{
    __shared__ unsigned short Zt[128 * 104];
    __shared__ unsigned short Wt[80 * 104];
    int tid = threadIdx.x;
    {
        const uint4* s = (const uint4*)Wh2t; uint4* d = (uint4*)Wt;
        for (int q = tid; q < 1040; q += 256) d[q] = s[q];
    }
    int rl = tid >> 1, half = tid & 1;
    size_t row = (size_t)blockIdx.x * 128 + rl;
    const float* mean = st2 + 144;
    const float* inv  = st2 + 216;
    const float4* zp = (const float4*)(z2 + row * 72) + half * 9;
    uint2* arow = (uint2*)(&Zt[rl * 104 + half * 36]);
    #pragma unroll
    for (int q = 0; q < 9; q++) {
        int k = half * 36 + q * 4;
        float4 v = zp[q];
        float a0 = fmaxf((v.x - mean[k  ]) * inv[k  ] * gh[k  ] + bh[k  ], 0.f);
        float a1 = fmaxf((v.y - mean[k+1]) * inv[k+1] * gh[k+1] + bh[k+1], 0.f);
        float a2 = fmaxf((v.z - mean[k+2]) * inv[k+2] * gh[k+2] + bh[k+2], 0.f);
        float a3 = fmaxf((v.w - mean[k+3]) * inv[k+3] * gh[k+3] + bh[k+3], 0.f);
        arow[q] = make_uint2(pk(a0, a1), pk(a2, a3));
    }
    uint2* prow = (uint2*)(&Zt[rl * 104]);
    #pragma unroll
    for (int q = 0; q < 4; q++) prow[18 + half * 4 + q] = make_uint2(0u, 0u);
    __syncthreads();

    int wv = tid >> 6, lane = tid & 63, c = lane & 15, quad = lane >> 4;
    f32x4 acc[2][5] = {};
    for (int kc = 0; kc < 3; kc++) {
        int k0 = kc * 32 + quad * 8;
        short8 a0 = *(const short8*)(&Zt[(wv * 32 + c) * 104 + k0]);
        short8 a1 = *(const short8*)(&Zt[(wv * 32 + 16 + c) * 104 + k0]);
        #pragma unroll
        for (int ct = 0; ct < 5; ct++) {
            short8 bf = *(const short8*)(&Wt[(ct * 16 + c) * 104 + k0]);
            acc[0][ct] = __builtin_amdgcn_mfma_f32_16x16x32_bf16(a0, bf, acc[0][ct], 0, 0, 0);
            acc[1][ct] = __builtin_amdgcn_mfma_f32_16x16x32_bf16(a1, bf, acc[1][ct], 0, 0, 0);
        }
    }
    size_t rbase = (size_t)blockIdx.x * 128 + wv * 32 + quad * 4;
    #pragma unroll
    for (int rt = 0; rt < 2; rt++)
        #pragma unroll
        for (int ct = 0; ct < 5; ct++) {
            int col = ct * 16 + c;
            if (col < 72) {
                float bias = bh2[col];
                #pragma unroll
                for (int r = 0; r < 4; r++) {
                    size_t gr = (rbase + rt * 16 + r);
                    hout[gr * 72 + col] = h[gr * 72 + col] + acc[rt][ct][r] + bias;
                }
            }
        }
    if (tid < 128) {
        size_t nrow = (size_t)blockIdx.x * 128 + tid;
        float cn = fmaxf(cnt[nrow], 1.f);
        float4 ag = *(const float4*)(agg + nrow * 4);
        float4 xv = *(const float4*)(x + nrow * 4);
        ((float4*)xout)[nrow] = make_float4(xv.x + ag.x / cn, xv.y + ag.y / cn,
                                            xv.z + ag.z / cn, xv.w + ag.w / cn);
    }
}

extern "C" void kernel_launch(void* const* d_in, const int* in_sizes, int n_in,
                              void* d_out, int out_size, void* d_ws, size_t ws_size,
                              hipStream_t stream)
{
    const float* h   = (const float*)d_in[0];
    const float* x   = (const float*)d_in[1];
    const int*   ei  = (const int*)d_in[2];
    const int*   ej  = (const int*)d_in[3];
    const float* na  = (const float*)d_in[4];
    const float* We1 = (const float*)d_in[5];
    const float* g1  = (const float*)d_in[6];
    const float* b1  = (const float*)d_in[7];
    const float* We2 = (const float*)d_in[8];
    const float* be2 = (const float*)d_in[9];
    const float* Wm  = (const float*)d_in[10];
    const float* bm  = (const float*)d_in[11];
    const float* Wx1 = (const float*)d_in[12];
    const float* bx1 = (const float*)d_in[13];
    const float* Wx2 = (const float*)d_in[14];
    const float* Wh1 = (const float*)d_in[15];
    const float* bh1 = (const float*)d_in[16];
    const float* gh  = (const float*)d_in[17];
    const float* bhp = (const float*)d_in[18];
    const float* Wh2 = (const float*)d_in[19];
    const float* bh2 = (const float*)d_in[20];

    float* out  = (float*)d_out;
    float* hout = out;
    float* xout = out + XOUT_OFF;
    float* m    = out + M_OFF;          // z1 scratch, then m
    float* ws   = (float*)d_ws;
    float* st1  = ws + ST1_OFF;
    float* st2  = ws + ST2_OFF;
    float* agg  = ws + AGG_OFF;
    float* cnt  = ws + CNT_OFF;
    float* magg = ws + MAGG_OFF;
    float* z2   = ws + Z2_OFF;
    unsigned short* wb = (unsigned short*)(ws + WB_OFF);

    hipMemsetAsync(d_ws, 0, (size_t)ZERO_FLOATS * sizeof(float), stream);
    k_prep<<<(WB_TOTAL + 255) / 256, 256, 0, stream>>>(We1, We2, Wx1, Wh1, Wh2, wb);
    k_edge_gemm1<<<ROWS_E / 128, 256, 0, stream>>>(h, x, ei, ej, wb + WE1T_OFF, m, st1);
    k_finalize<<<1, 128, 0, stream>>>(st1, 1.0f / (float)ROWS_E);
    k_edge_main<<<ROWS_E / 128, 256, 0, stream>>>(x, ei, ej, st1, g1, b1, be2, Wm, bm,
                                                  bx1, Wx2, wb + WE2T_OFF, wb + WX1T_OFF,
                                                  m, agg, cnt);
    k_magg<<<512, 256, 0, stream>>>(m, ei, magg);
    k_node_gemm1<<<ROWS_N / 128, 256, 0, stream>>>(h, na, magg, wb + WH1T_OFF, bh1, z2, st2);
    k_finalize<<<1, 128, 0, stream>>>(st2, 1.0f / (float)ROWS_N);
    k_node_final<<<ROWS_N / 128, 256, 0, stream>>>(h, x, z2, st2, gh, bhp,
                                                   wb + WH2T_OFF, bh2, agg, cnt, hout, xout);
}

// Round 3
// 680.102 us; speedup vs baseline: 1.0599x; 1.0599x over previous
//
#include <hip/hip_runtime.h>

#define BB 32
#define NN 128
#define EE 16384
#define ROWS_E (BB*EE)     // 524288
#define ROWS_N (BB*NN)     // 4096
#define EPS_BN 1e-5f

// d_out layout (floats): h_out, x_out, m
#define XOUT_OFF (ROWS_N*72)
#define M_OFF    (XOUT_OFF + ROWS_N*4)

// ws layout (floats)
#define ST1_OFF 0
#define ST2_OFF 512
#define AGG_OFF 1024
#define CNT_OFF (AGG_OFF + ROWS_N*4)
#define MAGG_OFF (CNT_OFF + ROWS_N)
#define Z2_OFF (MAGG_OFF + ROWS_N*72)     // 316416
#define ZERO_FLOATS Z2_OFF
#define WB_OFF (Z2_OFF + ROWS_N*72)       // 611328 floats; ushort region after

// transposed bf16 weight buffer (ushort offsets)
#define WE1T_OFF 0          // [80][168]
#define WE2T_OFF 13440      // [80][104]
#define WX1T_OFF 21760      // [80][104]
#define WH1T_OFF 30080      // [80][168]
#define WH2T_OFF 43520      // [80][104]
#define WB_TOTAL 51840

typedef __attribute__((ext_vector_type(8))) short short8;
typedef __attribute__((ext_vector_type(4))) float f32x4;

__device__ __forceinline__ float psi_f(float p) {
    return copysignf(log1pf(fabsf(p)), p);
}
__device__ __forceinline__ unsigned short f2bf(float f) {
    union { float f; unsigned u; } v; v.f = f;
    unsigned r = v.u + 0x7fffu + ((v.u >> 16) & 1u);
    return (unsigned short)(r >> 16);
}
__device__ __forceinline__ unsigned pk(float a, float b) {
    return (unsigned)f2bf(a) | ((unsigned)f2bf(b) << 16);
}

// ---------- weight prep: transpose + bf16, pad n->80, k->168/104 with zeros
__global__ void k_prep(const float* __restrict__ We1, const float* __restrict__ We2,
                       const float* __restrict__ Wx1, const float* __restrict__ Wh1,
                       const float* __restrict__ Wh2, unsigned short* __restrict__ wb)
{
    int idx = blockIdx.x * 256 + threadIdx.x;
    if (idx >= WB_TOTAL) return;
    const float* src; int off, n, k, K;
    if (idx < WE2T_OFF)      { off = idx;            n = off/168; k = off%168; src = We1; K = 146; }
    else if (idx < WH1T_OFF && idx >= WX1T_OFF) { off = idx - WX1T_OFF; n = off/104; k = off%104; src = Wx1; K = 72; }
    else if (idx < WX1T_OFF) { off = idx - WE2T_OFF; n = off/104; k = off%104; src = We2; K = 72; }
    else if (idx < WH2T_OFF) { off = idx - WH1T_OFF; n = off/168; k = off%168; src = Wh1; K = 148; }
    else                     { off = idx - WH2T_OFF; n = off/104; k = off%104; src = Wh2; K = 72; }
    float v = (n < 72 && k < K) ? src[k * 72 + n] : 0.f;
    wb[idx] = f2bf(v);
}

// ---------- shared staging: build feat tile (128 rows x 160, bf16) in At
__device__ __forceinline__ void stage_feat(
    unsigned short* At, const float* __restrict__ h, const float* __restrict__ x,
    const int* __restrict__ ei, const int* __restrict__ ej, int tid, int blk)
{
    int rl = tid >> 1, half = tid & 1;
    int row = blk * 128 + rl;
    int b = row >> 14;
    int i = ei[row], j = ej[row];
    int node = half ? j : i;
    const float4* hp = (const float4*)(h + (size_t)(b * 128 + node) * 72);
    uint2* arow = (uint2*)(&At[rl * 160 + half * 72]);
    #pragma unroll
    for (int q = 0; q < 18; q++) {
        float4 v = hp[q];
        arow[q] = make_uint2(pk(v.x, v.y), pk(v.z, v.w));
    }
    if (half == 0) {
        float4 xi = *(const float4*)(x + (size_t)(b * 128 + i) * 4);
        float4 xj = *(const float4*)(x + (size_t)(b * 128 + j) * 4);
        float d0 = xi.x - xj.x, d1 = xi.y - xj.y, d2 = xi.z - xj.z, d3 = xi.w - xj.w;
        float nrm = d0*d0 - d1*d1 - d2*d2 - d3*d3;
        float dot = xi.x*xj.x - xi.y*xj.y - xi.z*xj.z - xi.w*xj.w;
        *(unsigned*)(&At[rl * 160 + 144]) = pk(psi_f(nrm), psi_f(dot));
        unsigned* tp = (unsigned*)(&At[rl * 160 + 146]);
        tp[0] = 0u; tp[1] = 0u; tp[2] = 0u;      // k 146..151
    } else {
        unsigned* tp = (unsigned*)(&At[rl * 160 + 152]);
        tp[0] = 0u; tp[1] = 0u; tp[2] = 0u; tp[3] = 0u;  // k 152..159
    }
}

// ---------- Phase A: GEMM1 compute for BN stats only (NO z1 store)
__global__ __launch_bounds__(256, 4) void k_edge_stats(
    const float* __restrict__ h, const float* __restrict__ x,
    const int* __restrict__ ei, const int* __restrict__ ej,
    const unsigned short* __restrict__ We1t, float* __restrict__ st)
{
    __shared__ unsigned short At[128 * 160];
    int tid = threadIdx.x;
    stage_feat(At, h, x, ei, ej, tid, blockIdx.x);
    // no barrier: per-wave row ownership

    int wv = tid >> 6, lane = tid & 63, c = lane & 15, quad = lane >> 4;
    f32x4 acc[2][5] = {};
    for (int kc = 0; kc < 5; kc++) {
        int k0 = kc * 32 + quad * 8;
        short8 a0 = *(const short8*)(&At[(wv * 32 + c) * 160 + k0]);
        short8 a1 = *(const short8*)(&At[(wv * 32 + 16 + c) * 160 + k0]);
        #pragma unroll
        for (int ct = 0; ct < 5; ct++) {
            short8 bf = *(const short8*)(&We1t[(ct * 16 + c) * 168 + k0]);
            acc[0][ct] = __builtin_amdgcn_mfma_f32_16x16x32_bf16(a0, bf, acc[0][ct], 0, 0, 0);
            acc[1][ct] = __builtin_amdgcn_mfma_f32_16x16x32_bf16(a1, bf, acc[1][ct], 0, 0, 0);
        }
    }
    float* sredw = (float*)(&At[wv * 32 * 160]);   // reuse own wave's staged region
    #pragma unroll
    for (int ct = 0; ct < 5; ct++) {
        int col = ct * 16 + c;
        float s = 0.f, q = 0.f;
        #pragma unroll
        for (int rt = 0; rt < 2; rt++)
            #pragma unroll
            for (int r = 0; r < 4; r++) {
                float v = acc[rt][ct][r];
                s += v; q += v * v;
            }
        s += __shfl_xor(s, 16); s += __shfl_xor(s, 32);
        q += __shfl_xor(q, 16); q += __shfl_xor(q, 32);
        if (lane < 16 && col < 72) { sredw[col] = s; sredw[72 + col] = q; }
    }
    __syncthreads();
    if (tid < 144) {
        const float* a = (const float*)At;
        atomicAdd(&st[tid], a[tid] + a[2560 + tid] + a[5120 + tid] + a[7680 + tid]);
    }
}

__global__ void k_finalize(float* __restrict__ st, float inv_rows)
{
    int c = threadIdx.x;
    if (c < 72) {
        float mean = st[c] * inv_rows;
        float var  = st[72 + c] * inv_rows - mean * mean;
        st[144 + c] = mean;
        st[216 + c] = rsqrtf(var + EPS_BN);
    }
}

// ---------- Phase B: recompute GEMM1 -> in-register BN+ReLU -> GEMM2 -> gate -> m
//            -> GEMM3 -> g2 -> scatter agg/cnt.  z1 never touches memory.
// LDS: At slab (40960 B) reused per-wave: feat (GEMM1 A) -> BN'd z (GEMM2 A, stride 160)
// -> gated m (GEMM3 A). g2 handoff aliased into cols 96..159 of row wv*32.
__global__ __launch_bounds__(256, 4) void k_edge_fused(
    const float* __restrict__ h, const float* __restrict__ x,
    const int* __restrict__ ei, const int* __restrict__ ej,
    const float* __restrict__ st1, const float* __restrict__ g1, const float* __restrict__ b1,
    const float* __restrict__ be2, const float* __restrict__ Wm, const float* __restrict__ bm,
    const float* __restrict__ bx1, const float* __restrict__ Wx2,
    const unsigned short* __restrict__ We1t, const unsigned short* __restrict__ We2t,
    const unsigned short* __restrict__ Wx1t,
    float* __restrict__ m, float* __restrict__ agg, float* __restrict__ cnt)
{
    __shared__ unsigned short At[128 * 160];
    int tid = threadIdx.x;
    stage_feat(At, h, x, ei, ej, tid, blockIdx.x);
    // no barrier: per-wave row ownership

    int wv = tid >> 6, lane = tid & 63, c = lane & 15, quad = lane >> 4;
    // GEMM1 (recompute; bitwise-identical to k_edge_stats)
    f32x4 acc1[2][5] = {};
    for (int kc = 0; kc < 5; kc++) {
        int k0 = kc * 32 + quad * 8;
        short8 a0 = *(const short8*)(&At[(wv * 32 + c) * 160 + k0]);
        short8 a1 = *(const short8*)(&At[(wv * 32 + 16 + c) * 160 + k0]);
        #pragma unroll
        for (int ct = 0; ct < 5; ct++) {
            short8 bf = *(const short8*)(&We1t[(ct * 16 + c) * 168 + k0]);
            acc1[0][ct] = __builtin_amdgcn_mfma_f32_16x16x32_bf16(a0, bf, acc1[0][ct], 0, 0, 0);
            acc1[1][ct] = __builtin_amdgcn_mfma_f32_16x16x32_bf16(a1, bf, acc1[1][ct], 0, 0, 0);
        }
    }
    // in-register BN+ReLU, write bf16 A-fragments into own slab (stride 160)
    const float* mean = st1 + 144;
    const float* inv  = st1 + 216;
    #pragma unroll
    for (int ct = 0; ct < 5; ct++) {
        int col = ct * 16 + c;
        float mu = 0.f, iv = 0.f, ga = 0.f, be = 0.f;
        if (col < 72) { mu = mean[col]; iv = inv[col]; ga = g1[col]; be = b1[col]; }
        #pragma unroll
        for (int rt = 0; rt < 2; rt++)
            #pragma unroll
            for (int r = 0; r < 4; r++) {
                float a = (col < 72) ? fmaxf((acc1[rt][ct][r] - mu) * iv * ga + be, 0.f) : 0.f;
                int lrow = wv * 32 + rt * 16 + quad * 4 + r;
                At[lrow * 160 + col] = f2bf(a);
            }
    }
    {   // zero cols 80..95 of own rows (GEMM2/3 read k < 96)
        int r_ = lane >> 1, h_ = lane & 1;
        uint* zp = (uint*)&At[(wv * 32 + r_) * 160 + 80 + h_ * 8];
        zp[0] = 0u; zp[1] = 0u; zp[2] = 0u; zp[3] = 0u;
    }
    // GEMM2 (B from global)
    f32x4 acc2[2][5] = {};
    for (int kc = 0; kc < 3; kc++) {
        int k0 = kc * 32 + quad * 8;
        short8 a0 = *(const short8*)(&At[(wv * 32 + c) * 160 + k0]);
        short8 a1 = *(const short8*)(&At[(wv * 32 + 16 + c) * 160 + k0]);
        #pragma unroll
        for (int ct = 0; ct < 5; ct++) {
            short8 bf = *(const short8*)(&We2t[(ct * 16 + c) * 104 + k0]);
            acc2[0][ct] = __builtin_amdgcn_mfma_f32_16x16x32_bf16(a0, bf, acc2[0][ct], 0, 0, 0);
            acc2[1][ct] = __builtin_amdgcn_mfma_f32_16x16x32_bf16(a1, bf, acc2[1][ct], 0, 0, 0);
        }
    }
    // epilogue: t = relu(acc+be2); gate s = sum t*Wm
    float part[2][4] = {};
    float bm0 = bm[0];
    #pragma unroll
    for (int ct = 0; ct < 5; ct++) {
        int col = ct * 16 + c;
        float bias = (col < 72) ? be2[col] : 0.f;
        float wm   = (col < 72) ? Wm[col]  : 0.f;
        #pragma unroll
        for (int rt = 0; rt < 2; rt++)
            #pragma unroll
            for (int r = 0; r < 4; r++) {
                float t = fmaxf(acc2[rt][ct][r] + bias, 0.f);
                acc2[rt][ct][r] = t;
                part[rt][r] += t * wm;
            }
    }
    float sg[2][4];
    #pragma unroll
    for (int rt = 0; rt < 2; rt++)
        #pragma unroll
        for (int r = 0; r < 4; r++) {
            float s = part[rt][r];
            s += __shfl_xor(s, 1); s += __shfl_xor(s, 2);
            s += __shfl_xor(s, 4); s += __shfl_xor(s, 8);
            sg[rt][r] = 1.f / (1.f + expf(-(s + bm0)));
        }
    // m = t * gate: write global fp32 + bf16 back to own slab (cols 0..79)
    size_t rbase = (size_t)blockIdx.x * 128 + wv * 32 + quad * 4;
    #pragma unroll
    for (int rt = 0; rt < 2; rt++)
        #pragma unroll
        for (int ct = 0; ct < 5; ct++) {
            int col = ct * 16 + c;
            #pragma unroll
            for (int r = 0; r < 4; r++) {
                float mv = acc2[rt][ct][r] * sg[rt][r];
                int lrow = wv * 32 + rt * 16 + quad * 4 + r;
                At[lrow * 160 + col] = f2bf(mv);
                if (col < 72) m[(rbase + rt * 16 + r) * 72 + col] = mv;
            }
        }
    // GEMM3: u = m @ Wx1 (same wave's rows)
    f32x4 acc3[2][5] = {};
    for (int kc = 0; kc < 3; kc++) {
        int k0 = kc * 32 + quad * 8;
        short8 a0 = *(const short8*)(&At[(wv * 32 + c) * 160 + k0]);
        short8 a1 = *(const short8*)(&At[(wv * 32 + 16 + c) * 160 + k0]);
        #pragma unroll
        for (int ct = 0; ct < 5; ct++) {
            short8 bf = *(const short8*)(&Wx1t[(ct * 16 + c) * 104 + k0]);
            acc3[0][ct] = __builtin_amdgcn_mfma_f32_16x16x32_bf16(a0, bf, acc3[0][ct], 0, 0, 0);
            acc3[1][ct] = __builtin_amdgcn_mfma_f32_16x16x32_bf16(a1, bf, acc3[1][ct], 0, 0, 0);
        }
    }
    float part3[2][4] = {};
    #pragma unroll
    for (int ct = 0; ct < 5; ct++) {
        int col = ct * 16 + c;
        float bias = (col < 72) ? bx1[col] : 0.f;
        float wx   = (col < 72) ? Wx2[col] : 0.f;
        #pragma unroll
        for (int rt = 0; rt < 2; rt++)
            #pragma unroll
            for (int r = 0; r < 4; r++)
                part3[rt][r] += fmaxf(acc3[rt][ct][r] + bias, 0.f) * wx;
    }
    // g2 handoff: floats in cols 96..159 of row wv*32 (never read by GEMM2/3)
    float* gp = (float*)&At[(wv * 32) * 160 + 96];
    #pragma unroll
    for (int rt = 0; rt < 2; rt++)
        #pragma unroll
        for (int r = 0; r < 4; r++) {
            float s = part3[rt][r];
            s += __shfl_xor(s, 1); s += __shfl_xor(s, 2);
            s += __shfl_xor(s, 4); s += __shfl_xor(s, 8);
            if (c == 0) gp[rt * 16 + quad * 4 + r] = s;
        }
    __syncthreads();
    // scatter agg/cnt
    if (tid < 128) {
        size_t erow = (size_t)blockIdx.x * 128 + tid;
        int b = (int)(erow >> 14);
        int i2 = ei[erow], j2 = ej[erow];
        float g2 = *((float*)&At[((tid >> 5) * 32) * 160 + 96] + (tid & 31));
        float4 xi = *(const float4*)(x + (size_t)(b * 128 + i2) * 4);
        float4 xj = *(const float4*)(x + (size_t)(b * 128 + j2) * 4);
        float t0 = fminf(fmaxf((xi.x - xj.x) * g2, -100.f), 100.f);
        float t1 = fminf(fmaxf((xi.y - xj.y) * g2, -100.f), 100.f);
        float t2 = fminf(fmaxf((xi.z - xj.z) * g2, -100.f), 100.f);
        float t3 = fminf(fmaxf((xi.w - xj.w) * g2, -100.f), 100.f);
        float* ap = agg + (size_t)(b * 128 + i2) * 4;
        atomicAdd(ap + 0, t0); atomicAdd(ap + 1, t1);
        atomicAdd(ap + 2, t2); atomicAdd(ap + 3, t3);
        atomicAdd(cnt + (size_t)(b * 128 + i2), 1.f);
    }
}

// ---------- magg: segment-sum of m over edges, LDS-staged (256 blocks)
__global__ __launch_bounds__(256, 4) void k_magg(
    const float* __restrict__ m, const int* __restrict__ ei, float* __restrict__ magg)
{
    __shared__ float accum[128 * 72];
    int tid = threadIdx.x;
    for (int q = tid; q < 9216; q += 256) accum[q] = 0.f;
    __syncthreads();
    int b = blockIdx.x >> 3, chunk = blockIdx.x & 7;
    int wv = tid >> 6, lane = tid & 63;
    int ebase = b * 16384 + chunk * 2048;
    for (int e = wv; e < 2048; e += 4) {
        int erow = ebase + e;
        int node = ei[erow];
        const float* mr = m + (size_t)erow * 72;
        atomicAdd(&accum[node * 72 + lane], mr[lane]);
        if (lane < 8) atomicAdd(&accum[node * 72 + 64 + lane], mr[64 + lane]);
    }
    __syncthreads();
    float* mg = magg + (size_t)b * 9216;
    for (int q = tid; q < 9216; q += 256) atomicAdd(&mg[q], accum[q]);
}

// ---------- node GEMM1: z2 = [h, magg, node_attr] @ Wh1 + bh1 ; BN stats fused
__global__ __launch_bounds__(256) void k_node_gemm1(
    const float* __restrict__ h, const float* __restrict__ node_attr,
    const float* __restrict__ magg, const unsigned short* __restrict__ Wh1t,
    const float* __restrict__ bh1, float* __restrict__ z2, float* __restrict__ st)
{
    __shared__ unsigned short At[128 * 168];
    __shared__ unsigned short Wt[80 * 168];
    __shared__ float sred[4][144];
    int tid = threadIdx.x;
    {
        const uint4* s = (const uint4*)Wh1t; uint4* d = (uint4*)Wt;
        for (int q = tid; q < 1680; q += 256) d[q] = s[q];
    }
    int rl = tid >> 1, half = tid & 1;
    size_t row = (size_t)blockIdx.x * 128 + rl;
    const float4* sp = (const float4*)((half ? magg : h) + row * 72);
    uint2* arow = (uint2*)(&At[rl * 168 + half * 72]);
    #pragma unroll
    for (int q = 0; q < 18; q++) {
        float4 v = sp[q];
        arow[q] = make_uint2(pk(v.x, v.y), pk(v.z, v.w));
    }
    if (half) {
        float4 na = *(const float4*)(node_attr + row * 4);
        *(unsigned*)(&At[rl * 168 + 144]) = pk(na.x, na.y);
        *(unsigned*)(&At[rl * 168 + 146]) = pk(na.z, na.w);
        unsigned* tailp = (unsigned*)(&At[rl * 168 + 148]);
        #pragma unroll
        for (int q = 0; q < 10; q++) tailp[q] = 0u;
    }
    __syncthreads();

    int wv = tid >> 6, lane = tid & 63, c = lane & 15, quad = lane >> 4;
    f32x4 acc[2][5] = {};
    for (int kc = 0; kc < 5; kc++) {
        int k0 = kc * 32 + quad * 8;
        short8 a0 = *(const short8*)(&At[(wv * 32 + c) * 168 + k0]);
        short8 a1 = *(const short8*)(&At[(wv * 32 + 16 + c) * 168 + k0]);
        #pragma unroll
        for (int ct = 0; ct < 5; ct++) {
            short8 bf = *(const short8*)(&Wt[(ct * 16 + c) * 168 + k0]);
            acc[0][ct] = __builtin_amdgcn_mfma_f32_16x16x32_bf16(a0, bf, acc[0][ct], 0, 0, 0);
            acc[1][ct] = __builtin_amdgcn_mfma_f32_16x16x32_bf16(a1, bf, acc[1][ct], 0, 0, 0);
        }
    }
    size_t rbase = (size_t)blockIdx.x * 128 + wv * 32 + quad * 4;
    #pragma unroll
    for (int ct = 0; ct < 5; ct++) {
        int col = ct * 16 + c;
        float bias = (col < 72) ? bh1[col] : 0.f;
        float s = 0.f, q = 0.f;
        #pragma unroll
        for (int rt = 0; rt < 2; rt++) {
            float* op = z2 + (rbase + rt * 16) * 72 + col;
            #pragma unroll
            for (int r = 0; r < 4; r++) {
                float v = acc[rt][ct][r] + bias;
                if (col < 72) op[(size_t)r * 72] = v;
                s += v; q += v * v;
            }
        }
        s += __shfl_xor(s, 16); s += __shfl_xor(s, 32);
        q += __shfl_xor(q, 16); q += __shfl_xor(q, 32);
        if (lane < 16 && col < 72) { sred[wv][col] = s; sred[wv][72 + col] = q; }
    }
    __syncthreads();
    if (tid < 144)
        atomicAdd(&st[tid], sred[0][tid] + sred[1][tid] + sred[2][tid] + sred[3][tid]);
}

// ---------- node final: BN2+ReLU -> MFMA @Wh2 + bh2 + h ; x_out
__global__ __launch_bounds__(256) void k_node_final(
    const float* __restrict__ h, const float* __restrict__ x,
    const float* __restrict__ z2, const float* __restrict__ st2,
    const float* __restrict__ gh, const float* __restrict__ bh,
    const unsigned short* __restrict__ Wh2t, const float* __restrict__ bh2,
    const float* __restrict__ agg, const float* __restrict__ cnt,
    float* __restrict__ hout, float* __restrict__ xout)
{
    __shared__ unsigned short Zt[128 * 104];
    __shared__ unsigned short Wt[80 * 104];
    int tid = threadIdx.x;
    {
        const uint4* s = (const uint4*)Wh2t; uint4* d = (uint4*)Wt;
        for (int q = tid; q < 1040; q += 256) d[q] = s[q];
    }
    int rl = tid >> 1, half = tid & 1;
    size_t row = (size_t)blockIdx.x * 128 + rl;
    const float* mean = st2 + 144;
    const float* inv  = st2 + 216;
    const float4* zp = (const float4*)(z2 + row * 72) + half * 9;
    uint2* arow = (uint2*)(&Zt[rl * 104 + half * 36]);
    #pragma unroll
    for (int q = 0; q < 9; q++) {
        int k = half * 36 + q * 4;
        float4 v = zp[q];
        float a0 = fmaxf((v.x - mean[k  ]) * inv[k  ] * gh[k  ] + bh[k  ], 0.f);
        float a1 = fmaxf((v.y - mean[k+1]) * inv[k+1] * gh[k+1] + bh[k+1], 0.f);
        float a2 = fmaxf((v.z - mean[k+2]) * inv[k+2] * gh[k+2] + bh[k+2], 0.f);
        float a3 = fmaxf((v.w - mean[k+3]) * inv[k+3] * gh[k+3] + bh[k+3], 0.f);
        arow[q] = make_uint2(pk(a0, a1), pk(a2, a3));
    }
    uint2* prow = (uint2*)(&Zt[rl * 104]);
    #pragma unroll
    for (int q = 0; q < 4; q++) prow[18 + half * 4 + q] = make_uint2(0u, 0u);
    __syncthreads();

    int wv = tid >> 6, lane = tid & 63, c = lane & 15, quad = lane >> 4;
    f32x4 acc[2][5] = {};
    for (int kc = 0; kc < 3; kc++) {
        int k0 = kc * 32 + quad * 8;
        short8 a0 = *(const short8*)(&Zt[(wv * 32 + c) * 104 + k0]);
        short8 a1 = *(const short8*)(&Zt[(wv * 32 + 16 + c) * 104 + k0]);
        #pragma unroll
        for (int ct = 0; ct < 5; ct++) {
            short8 bf = *(const short8*)(&Wt[(ct * 16 + c) * 104 + k0]);
            acc[0][ct] = __builtin_amdgcn_mfma_f32_16x16x32_bf16(a0, bf, acc[0][ct], 0, 0, 0);
            acc[1][ct] = __builtin_amdgcn_mfma_f32_16x16x32_bf16(a1, bf, acc[1][ct], 0, 0, 0);
        }
    }
    size_t rbase = (size_t)blockIdx.x * 128 + wv * 32 + quad * 4;
    #pragma unroll
    for (int rt = 0; rt < 2; rt++)
        #pragma unroll
        for (int ct = 0; ct < 5; ct++) {
            int col = ct * 16 + c;
            if (col < 72) {
                float bias = bh2[col];
                #pragma unroll
                for (int r = 0; r < 4; r++) {
                    size_t gr = (rbase + rt * 16 + r);
                    hout[gr * 72 + col] = h[gr * 72 + col] + acc[rt][ct][r] + bias;
                }
            }
        }
    if (tid < 128) {
        size_t nrow = (size_t)blockIdx.x * 128 + tid;
        float cn = fmaxf(cnt[nrow], 1.f);
        float4 ag = *(const float4*)(agg + nrow * 4);
        float4 xv = *(const float4*)(x + nrow * 4);
        ((float4*)xout)[nrow] = make_float4(xv.x + ag.x / cn, xv.y + ag.y / cn,
                                            xv.z + ag.z / cn, xv.w + ag.w / cn);
    }
}

extern "C" void kernel_launch(void* const* d_in, const int* in_sizes, int n_in,
                              void* d_out, int out_size, void* d_ws, size_t ws_size,
                              hipStream_t stream)
{
    const float* h   = (const float*)d_in[0];
    const float* x   = (const float*)d_in[1];
    const int*   ei  = (const int*)d_in[2];
    const int*   ej  = (const int*)d_in[3];
    const float* na  = (const float*)d_in[4];
    const float* We1 = (const float*)d_in[5];
    const float* g1  = (const float*)d_in[6];
    const float* b1  = (const float*)d_in[7];
    const float* We2 = (const float*)d_in[8];
    const float* be2 = (const float*)d_in[9];
    const float* Wm  = (const float*)d_in[10];
    const float* bm  = (const float*)d_in[11];
    const float* Wx1 = (const float*)d_in[12];
    const float* bx1 = (const float*)d_in[13];
    const float* Wx2 = (const float*)d_in[14];
    const float* Wh1 = (const float*)d_in[15];
    const float* bh1 = (const float*)d_in[16];
    const float* gh  = (const float*)d_in[17];
    const float* bhp = (const float*)d_in[18];
    const float* Wh2 = (const float*)d_in[19];
    const float* bh2 = (const float*)d_in[20];

    float* out  = (float*)d_out;
    float* hout = out;
    float* xout = out + XOUT_OFF;
    float* m    = out + M_OFF;
    float* ws   = (float*)d_ws;
    float* st1  = ws + ST1_OFF;
    float* st2  = ws + ST2_OFF;
    float* agg  = ws + AGG_OFF;
    float* cnt  = ws + CNT_OFF;
    float* magg = ws + MAGG_OFF;
    float* z2   = ws + Z2_OFF;
    unsigned short* wb = (unsigned short*)(ws + WB_OFF);

    hipMemsetAsync(d_ws, 0, (size_t)ZERO_FLOATS * sizeof(float), stream);
    k_prep<<<(WB_TOTAL + 255) / 256, 256, 0, stream>>>(We1, We2, Wx1, Wh1, Wh2, wb);
    k_edge_stats<<<ROWS_E / 128, 256, 0, stream>>>(h, x, ei, ej, wb + WE1T_OFF, st1);
    k_finalize<<<1, 128, 0, stream>>>(st1, 1.0f / (float)ROWS_E);
    k_edge_fused<<<ROWS_E / 128, 256, 0, stream>>>(h, x, ei, ej, st1, g1, b1, be2, Wm, bm,
                                                   bx1, Wx2, wb + WE1T_OFF, wb + WE2T_OFF,
                                                   wb + WX1T_OFF, m, agg, cnt);
    k_magg<<<256, 256, 0, stream>>>(m, ei, magg);
    k_node_gemm1<<<ROWS_N / 128, 256, 0, stream>>>(h, na, magg, wb + WH1T_OFF, bh1, z2, st2);
    k_finalize<<<1, 128, 0, stream>>>(st2, 1.0f / (float)ROWS_N);
    k_node_final<<<ROWS_N / 128, 256, 0, stream>>>(h, x, z2, st2, gh, bhp,
                                                   wb + WH2T_OFF, bh2, agg, cnt, hout, xout);
}